// Round 9
// baseline (1225.000 us; speedup 1.0000x reference)
//
#include <hip/hip_runtime.h>
#include <hip/hip_fp16.h>

typedef _Float16 f16;
typedef __attribute__((ext_vector_type(2))) _Float16 f16x2;
typedef __attribute__((ext_vector_type(8))) _Float16 f16x8;
typedef __attribute__((ext_vector_type(4))) float f32x4;

constexpr int BATCH = 64;
constexpr int TLEN  = 2048;
constexpr int NIN   = 128;
constexpr int NHID  = 256;
constexpr int NOUT  = 128;
constexpr long MROWS = (long)BATCH * TLEN;   // 131072
constexpr float CSC = 2.8853900817779268f;   // 2*log2(e): 2^(CSC*z) = e^(2z)

__device__ __forceinline__ float exp2f_hw(float x) {
#if __has_builtin(__builtin_amdgcn_exp2f)
  return __builtin_amdgcn_exp2f(x);
#else
  return __expf(x * 0.6931471805599453f);
#endif
}
__device__ __forceinline__ float rcp_hw(float x) {
#if __has_builtin(__builtin_amdgcn_rcpf)
  return __builtin_amdgcn_rcpf(x);
#else
  return 1.0f / x;
#endif
}
__device__ __forceinline__ float fdot2f(unsigned int a, unsigned int b, float c) {
#if __has_builtin(__builtin_amdgcn_fdot2)
  return __builtin_amdgcn_fdot2(__builtin_bit_cast(f16x2, a),
                                __builtin_bit_cast(f16x2, b), c, false);
#else
  f16x2 av = __builtin_bit_cast(f16x2, a);
  f16x2 bv = __builtin_bit_cast(f16x2, b);
  return c + (float)av.x * (float)bv.x + (float)av.y * (float)bv.y;
#endif
}
// DPP: 0xB1 = quad_perm(1,0,3,2) -> lane^1 ; 0x4E = quad_perm(2,3,0,1) -> lane^2
template<int CTRL>
__device__ __forceinline__ float dpp_xor(float x) {
  int r = __builtin_amdgcn_update_dpp(0, __builtin_bit_cast(int, x),
                                      CTRL, 0xF, 0xF, true);
  return __builtin_bit_cast(float, r);
}
// barrier that makes LDS writes visible WITHOUT draining vmcnt (global
// stores / prefetch loads keep flying across steps)
__device__ __forceinline__ void barrier_lds() {
  asm volatile("s_waitcnt lgkmcnt(0)" ::: "memory");
  __builtin_amdgcn_s_barrier();
  asm volatile("" ::: "memory");
}

// ---------------------------------------------------------------------------
// Weight convert + hi/lo split. Whh pre-scaled by CSC (tanh exp2 fold).
// f16 layout: WinH[32768] WinL[32768] WihH[65536] WihL[65536] Whh[65536] Wout[32768]
// (unchanged, proven)
// ---------------------------------------------------------------------------
__global__ void cvt_weights(const float* __restrict__ Win, const float* __restrict__ Wih,
                            const float* __restrict__ Whh, const float* __restrict__ Wout,
                            f16* __restrict__ dst) {
  int i = blockIdx.x * blockDim.x + threadIdx.x;
  if (i < 32768) {
    float v = Win[i]; f16 h = (f16)v;
    dst[i] = h; dst[32768 + i] = (f16)(v - (float)h);
  } else if (i < 98304) {
    int j = i - 32768; float v = Wih[j]; f16 h = (f16)v;
    dst[65536 + j] = h; dst[131072 + j] = (f16)(v - (float)h);
  } else if (i < 163840) {
    int j = i - 98304; dst[196608 + j] = (f16)(CSC * Whh[j]);
  } else if (i < 196608) {
    int j = i - 163840; dst[262144 + j] = (f16)Wout[j];
  }
}

// ---------------------------------------------------------------------------
// GEMM: C[m,n] = act( sum_k A[m,k]*W[n,k] + bias[n] )   (R20 version, proven:
// A-side lo path removed; B-side hi/lo kept — dominant W-quant term corrected)
// ---------------------------------------------------------------------------
constexpr int BM = 64, BN = 64, BK = 64;

template<int MODE>
__global__ __launch_bounds__(256)
void gemm_kernel(const void* __restrict__ Ap,
                 const f16* __restrict__ Bh_, const f16* __restrict__ Bl_,
                 const float* __restrict__ bias, const float* __restrict__ bias2,
                 void* __restrict__ Cp, int K, int N) {
  __shared__ __align__(16) f16 Ah[BM][BK + 8];
  __shared__ __align__(16) f16 Bh[BN][BK + 8];
  __shared__ __align__(16) f16 Bl[BN][BK + 8];

  const int tid  = threadIdx.x;
  const int lane = tid & 63;
  const int wid  = tid >> 6;
  const int wm = wid >> 1, wn = wid & 1;
  const long row0 = (long)blockIdx.x * BM;
  const int  col0 = blockIdx.y * BN;
  const int r  = tid >> 2;
  const int cc = (tid & 3) * 16;

  f32x4 acc[2][2] = {};

  for (int k0 = 0; k0 < K; k0 += BK) {
    if constexpr (MODE == 1) {
      const float* src = (const float*)Ap + (row0 + r) * (long)K + k0 + cc;
      #pragma unroll
      for (int q = 0; q < 4; ++q) {
        float4 v = ((const float4*)src)[q];
        Ah[r][cc + 4*q + 0] = (f16)v.x;
        Ah[r][cc + 4*q + 1] = (f16)v.y;
        Ah[r][cc + 4*q + 2] = (f16)v.z;
        Ah[r][cc + 4*q + 3] = (f16)v.w;
      }
    } else {
      const f16* sh = (const f16*)Ap + (row0 + r) * (long)K + k0 + cc;
      *(uint4*)&Ah[r][cc]     = *(const uint4*)sh;
      *(uint4*)&Ah[r][cc + 8] = *(const uint4*)(sh + 8);
    }
    {
      const f16* sh = Bh_ + (col0 + r) * (long)K + k0 + cc;
      *(uint4*)&Bh[r][cc]     = *(const uint4*)sh;
      *(uint4*)&Bh[r][cc + 8] = *(const uint4*)(sh + 8);
      if constexpr (MODE != 3) {
        const f16* sl = Bl_ + (col0 + r) * (long)K + k0 + cc;
        *(uint4*)&Bl[r][cc]     = *(const uint4*)sl;
        *(uint4*)&Bl[r][cc + 8] = *(const uint4*)(sl + 8);
      }
    }
    __syncthreads();

    #pragma unroll
    for (int ks = 0; ks < BK / 32; ++ks) {
      const int ko = ks * 32 + (lane >> 4) * 8;
      const int ra = wm * 32 + (lane & 15);
      const int rb = wn * 32 + (lane & 15);
      f16x8 a0 = *(const f16x8*)&Ah[ra][ko];
      f16x8 a1 = *(const f16x8*)&Ah[ra + 16][ko];
      f16x8 b0 = *(const f16x8*)&Bh[rb][ko];
      f16x8 b1 = *(const f16x8*)&Bh[rb + 16][ko];
      acc[0][0] = __builtin_amdgcn_mfma_f32_16x16x32_f16(a0, b0, acc[0][0], 0, 0, 0);
      acc[0][1] = __builtin_amdgcn_mfma_f32_16x16x32_f16(a0, b1, acc[0][1], 0, 0, 0);
      acc[1][0] = __builtin_amdgcn_mfma_f32_16x16x32_f16(a1, b0, acc[1][0], 0, 0, 0);
      acc[1][1] = __builtin_amdgcn_mfma_f32_16x16x32_f16(a1, b1, acc[1][1], 0, 0, 0);
      if constexpr (MODE != 3) {
        f16x8 lb0 = *(const f16x8*)&Bl[rb][ko];
        f16x8 lb1 = *(const f16x8*)&Bl[rb + 16][ko];
        acc[0][0] = __builtin_amdgcn_mfma_f32_16x16x32_f16(a0, lb0, acc[0][0], 0, 0, 0);
        acc[0][1] = __builtin_amdgcn_mfma_f32_16x16x32_f16(a0, lb1, acc[0][1], 0, 0, 0);
        acc[1][0] = __builtin_amdgcn_mfma_f32_16x16x32_f16(a1, lb0, acc[1][0], 0, 0, 0);
        acc[1][1] = __builtin_amdgcn_mfma_f32_16x16x32_f16(a1, lb1, acc[1][1], 0, 0, 0);
      }
    }
    __syncthreads();
  }

  #pragma unroll
  for (int mi = 0; mi < 2; ++mi)
    #pragma unroll
    for (int ni = 0; ni < 2; ++ni)
      #pragma unroll
      for (int q = 0; q < 4; ++q) {
        long row = row0 + wm * 32 + mi * 16 + (lane >> 4) * 4 + q;
        int  col = col0 + wn * 32 + ni * 16 + (lane & 15);
        if constexpr (MODE == 1) {
          float v = fmaxf(acc[mi][ni][q] + bias[col], 0.0f);
          ((f16*)Cp)[row * (long)N + col] = (f16)v;
        } else if constexpr (MODE == 2) {
          float v = (acc[mi][ni][q] + bias[col] + bias2[col]) * CSC;
          ((float*)Cp)[row * (long)N + col] = v;
        } else {
          ((float*)Cp)[row * (long)N + col] = acc[mi][ni][q] + bias[col];
        }
      }
}

// ---------------------------------------------------------------------------
// Recurrence R21 = R12 structure + 25% of Whh moved to the LDS pipe.
//
// Port model (fits all 8 rounds): step time = per-CU weight re-stream of
// 128 KB through the ~128 B/cyc L1/L2 fill path = 1024 cyc ~= measured 1037.
// Register residency is compiler-unreachable (R16-R19). Remaining lever:
// SPLIT the stream across two independent pipes. 16 of 64 words/lane
// (wr0[0..7], wr1[0..7]) live in LDS (32 KB: plane p*8192 + tid*16,
// full-width stride-16B reads ~8-12 cyc/instr); the other 48 words stay as
// the usual in-loop global remat (96 KB/step -> ~768 cyc of L2). LDS pipe:
// ~350 cyc h-reads + ~320 cyc weight-reads = ~670 cyc, concurrent with L2.
// Predicted step ~800-850 cyc.
// The in-loop LDS weight loads are kept in-loop (NOT LICM-hoisted-then-
// spilled, the R16 failure mode) via an opaque asm "+v" on the ADDRESS
// OFFSETS each step; the loads themselves stay normal C++ LDS reads so the
// compiler's lgkmcnt bookkeeping stays correct (no rule-18 hazard).
// Values are bit-identical to R12/R20 -> absmax must stay 0.00390625.
// Everything else verbatim R12 (887us proven).
// ---------------------------------------------------------------------------
#define STEP(K, SRC, DST, P) do {                                            \
  unsigned int hs[32];                                                       \
  _Pragma("unroll")                                                          \
  for (int q = 0; q < 8; ++q) {                                              \
    uint4 v = *(const uint4*)((SRC) + roff[q]);                              \
    hs[4*q+0] = v.x; hs[4*q+1] = v.y; hs[4*q+2] = v.z; hs[4*q+3] = v.w;      \
  }                                                                          \
  /* LDS-resident weight slice: opaque offsets defeat LICM/CSE so the      */\
  /* ds_read_b128s stay inside the loop (LDS pipe, concurrent with L2).    */\
  int wq0 = 0, wq1 = 8192, wq2 = 16384, wq3 = 24576;                         \
  asm volatile("" : "+v"(wq0), "+v"(wq1), "+v"(wq2), "+v"(wq3));             \
  uint4 lv0 = *(const uint4*)(wl + wq0);                                     \
  uint4 lv1 = *(const uint4*)(wl + wq1);                                     \
  uint4 lv2 = *(const uint4*)(wl + wq2);                                     \
  uint4 lv3 = *(const uint4*)(wl + wq3);                                     \
  unsigned int wz0[8] = {lv0.x, lv0.y, lv0.z, lv0.w,                         \
                         lv1.x, lv1.y, lv1.z, lv1.w};                        \
  unsigned int wz1[8] = {lv2.x, lv2.y, lv2.z, lv2.w,                         \
                         lv3.x, lv3.y, lv3.z, lv3.w};                        \
  float a0a = 0.f, a1a = 0.f, a0b = 0.f, a1b = 0.f;                          \
  _Pragma("unroll")                                                          \
  for (int kk = 0; kk < 8; ++kk) {                                           \
    a0a = fdot2f(wz0[kk], hs[kk], a0a);                                      \
    a1a = fdot2f(wz1[kk], hs[kk], a1a);                                      \
  }                                                                          \
  _Pragma("unroll")                                                          \
  for (int kk = 8; kk < 16; ++kk) {                                          \
    a0a = fdot2f(wr0[kk], hs[kk], a0a);                                      \
    a1a = fdot2f(wr1[kk], hs[kk], a1a);                                      \
  }                                                                          \
  _Pragma("unroll")                                                          \
  for (int kk = 16; kk < 32; ++kk) {                                         \
    a0b = fdot2f(wr0[kk], hs[kk], a0b);                                      \
    a1b = fdot2f(wr1[kk], hs[kk], a1b);                                      \
  }                                                                          \
  float a0 = a0a + a0b, a1 = a1a + a1b;                                      \
  float keep = s0 ? a1 : a0;                                                 \
  float send = s0 ? a0 : a1;                                                 \
  float t1 = keep + dpp_xor<0xB1>(send);    /* xor1, quad_perm(1,0,3,2) */   \
  float z  = t1 + dpp_xor<0x4E>(t1) + (P);  /* xor2 all-reduce */            \
  float ee = exp2f_hw(z);                                                    \
  float hv = fmaxf(fmaf(-2.0f, rcp_hw(ee + 1.0f), 1.0f), 0.0f);              \
  f16 hf = (f16)hv;                                                          \
  if (!s1) *(f16*)((DST) + wo) = hf;        /* LDS next-h (one copy) */      \
  else     hp[(K) * 256] = hf;              /* h16 global (other copy) */    \
} while (0)

__global__ __launch_bounds__(512, 1)
void rec_kernel(const float* __restrict__ pre, const f16* __restrict__ W2,
                f16* __restrict__ h16) {
  const int b    = blockIdx.x;
  const int tid  = threadIdx.x;
  const int lane = tid & 63;
  const int w    = tid >> 6;                 // 0..7
  const int jj   = lane & 3;                 // k-slice [64jj,64jj+64)
  const int grp  = (lane >> 2) | (w << 4);   // 0..127
  const int s0   = lane & 1;
  const int s1   = (lane >> 1) & 1;
  const int G    = grp * 2;
  const int g    = G + s0;                   // owned output (dup with lane^2)

  __shared__ __align__(16) char hb[2][512];
  __shared__ __align__(16) unsigned int wlds[4][512][4];   // 32 KB weight slice

  // W rows G, G+1, k in [64jj,64jj+64), chunk-rotated to match LDS reads
  unsigned int wr0[32], wr1[32];
  #pragma unroll
  for (int q = 0; q < 8; ++q) {
    int c = (q + 2 * jj) & 7;
    uint4 v0 = *(const uint4*)(W2 + (size_t)G * 256 + 64 * jj + 8 * c);
    uint4 v1 = *(const uint4*)(W2 + (size_t)(G + 1) * 256 + 64 * jj + 8 * c);
    wr0[4*q+0] = v0.x; wr0[4*q+1] = v0.y; wr0[4*q+2] = v0.z; wr0[4*q+3] = v0.w;
    wr1[4*q+0] = v1.x; wr1[4*q+1] = v1.y; wr1[4*q+2] = v1.z; wr1[4*q+3] = v1.w;
  }
  // stash words 0..7 of each row (q=0,1 rotated chunks) in LDS — the slice
  // the in-loop STEP reads from the LDS pipe instead of the L2 stream
  *(uint4*)&wlds[0][tid][0] = make_uint4(wr0[0], wr0[1], wr0[2], wr0[3]);
  *(uint4*)&wlds[1][tid][0] = make_uint4(wr0[4], wr0[5], wr0[6], wr0[7]);
  *(uint4*)&wlds[2][tid][0] = make_uint4(wr1[0], wr1[1], wr1[2], wr1[3]);
  *(uint4*)&wlds[3][tid][0] = make_uint4(wr1[4], wr1[5], wr1[6], wr1[7]);

  if (tid < 128) ((unsigned int*)&hb[0][0])[tid] = 0u;
  __syncthreads();

  int roff[8];
  #pragma unroll
  for (int q = 0; q < 8; ++q) roff[q] = 128 * jj + 16 * ((q + 2 * jj) & 7);
  const int wo = 2 * g;
  const char* wl = (const char*)&wlds[0][0][0] + tid * 16;

  const float* pp  = pre + (size_t)b * TLEN * 256 + g;
  f16*         hp  = h16 + (size_t)b * TLEN * 256 + g;
  const float* ppf = pp + 1024;              // t+4 prefetch pointer

  float p0 = pp[0];
  float p1 = pp[256];
  float p2 = pp[512];
  float p3 = pp[768];

  const char* hb0 = &hb[0][0];
  char*       hb1 = &hb[1][0];

  #pragma unroll 1
  for (int t = 0; t < TLEN; t += 4) {
    // issue next-quad prefetch early; lands during these 4 steps
    float n0 = ppf[0];
    float n1 = ppf[256];
    float n2 = ppf[512];
    float n3 = ppf[768];
    STEP(0, hb0, hb1, p0);
    barrier_lds();
    STEP(1, hb1, (char*)hb0, p1);
    barrier_lds();
    STEP(2, hb0, hb1, p2);
    barrier_lds();
    STEP(3, hb1, (char*)hb0, p3);
    barrier_lds();
    p0 = n0; p1 = n1; p2 = n2; p3 = n3;
    ppf += 1024;
    hp  += 1024;
  }
}

// ---------------------------------------------------------------------------
// h16 -> f32 hidden (parallel, HBM-bound; removes the f32 store from rec's
// serial loop). Proven in R2.
// ---------------------------------------------------------------------------
__global__ __launch_bounds__(256)
void cvt_h(const f16* __restrict__ src, float* __restrict__ dst, long n) {
  long i0 = ((long)blockIdx.x * 256 + threadIdx.x) * 8;
  long stride = (long)gridDim.x * 256 * 8;
  for (long i = i0; i < n; i += stride) {
    f16x8 v = *(const f16x8*)(src + i);
    float4 a = {(float)v[0], (float)v[1], (float)v[2], (float)v[3]};
    float4 bq = {(float)v[4], (float)v[5], (float)v[6], (float)v[7]};
    *(float4*)(dst + i) = a;
    *(float4*)(dst + i + 4) = bq;
  }
}

// ---------------------------------------------------------------------------
extern "C" void kernel_launch(void* const* d_in, const int* in_sizes, int n_in,
                              void* d_out, int out_size, void* d_ws, size_t ws_size,
                              hipStream_t stream) {
  const float* input = (const float*)d_in[0];
  const float* W_in  = (const float*)d_in[1];
  const float* b_in  = (const float*)d_in[2];
  const float* W_ih  = (const float*)d_in[3];
  const float* b_ih  = (const float*)d_in[4];
  const float* W_hh  = (const float*)d_in[5];
  const float* b_hh  = (const float*)d_in[6];
  const float* W_out = (const float*)d_in[7];
  const float* b_out = (const float*)d_in[8];

  float* hidden = (float*)d_out;                   // [64,2048,256] f32
  float* outp   = (float*)d_out + MROWS * NHID;    // [64,2048,128] f32

  char* ws = (char*)d_ws;
  const size_t xh_off  = 0;
  const size_t xl_off  = (size_t)MROWS * NHID * 2;       // 64 MiB (unused now)
  const size_t pre_off = xl_off * 2;                     // 128 MiB in
  const size_t w_off   = pre_off + (size_t)MROWS * NHID * 4;
  const size_t need    = w_off + 294912ull * 2;
  if (ws_size < need) return;

  f16*   x_hi  = (f16*)(ws + xh_off);
  float* pre   = (float*)(ws + pre_off);                 // plain [b][t][g], scaled
  f16*   wbase = (f16*)(ws + w_off);
  f16 *WinH = wbase,           *WinL = wbase + 32768;
  f16 *WihH = wbase + 65536,   *WihL = wbase + 131072;
  f16 *Whh16 = wbase + 196608, *Wout16 = wbase + 262144;
  f16* h16 = x_hi;   // alias: x consumed by G2 before rec writes h16

  cvt_weights<<<768, 256, 0, stream>>>(W_in, W_ih, W_hh, W_out, wbase);

  dim3 g12((unsigned)(MROWS / BM), NHID / BN);
  gemm_kernel<1><<<g12, 256, 0, stream>>>(input, WinH, WinL, b_in, nullptr,
                                          x_hi, NIN, NHID);
  gemm_kernel<2><<<g12, 256, 0, stream>>>(x_hi, WihH, WihL, b_ih, b_hh,
                                          pre, NHID, NHID);

  rec_kernel<<<BATCH, 512, 0, stream>>>(pre, Whh16, h16);

  cvt_h<<<2048, 256, 0, stream>>>(h16, hidden, MROWS * NHID);

  dim3 g3((unsigned)(MROWS / BM), NOUT / BN);
  gemm_kernel<3><<<g3, 256, 0, stream>>>(h16, Wout16, nullptr, b_out, nullptr,
                                         outp, NHID, NOUT);
}

// Round 10
// 1049.855 us; speedup vs baseline: 1.1668x; 1.1668x over previous
//
#include <hip/hip_runtime.h>
#include <hip/hip_fp16.h>

typedef _Float16 f16;
typedef __attribute__((ext_vector_type(2))) _Float16 f16x2;
typedef __attribute__((ext_vector_type(8))) _Float16 f16x8;
typedef __attribute__((ext_vector_type(4))) float f32x4;

constexpr int BATCH = 64;
constexpr int TLEN  = 2048;
constexpr int NIN   = 128;
constexpr int NHID  = 256;
constexpr int NOUT  = 128;
constexpr long MROWS = (long)BATCH * TLEN;   // 131072
constexpr float CSC = 2.8853900817779268f;   // 2*log2(e): 2^(CSC*z) = e^(2z)

__device__ __forceinline__ float exp2f_hw(float x) {
#if __has_builtin(__builtin_amdgcn_exp2f)
  return __builtin_amdgcn_exp2f(x);
#else
  return __expf(x * 0.6931471805599453f);
#endif
}
__device__ __forceinline__ float rcp_hw(float x) {
#if __has_builtin(__builtin_amdgcn_rcpf)
  return __builtin_amdgcn_rcpf(x);
#else
  return 1.0f / x;
#endif
}
__device__ __forceinline__ float fdot2f(unsigned int a, unsigned int b, float c) {
#if __has_builtin(__builtin_amdgcn_fdot2)
  return __builtin_amdgcn_fdot2(__builtin_bit_cast(f16x2, a),
                                __builtin_bit_cast(f16x2, b), c, false);
#else
  f16x2 av = __builtin_bit_cast(f16x2, a);
  f16x2 bv = __builtin_bit_cast(f16x2, b);
  return c + (float)av.x * (float)bv.x + (float)av.y * (float)bv.y;
#endif
}
// DPP: 0xB1 = quad_perm(1,0,3,2) -> lane^1 ; 0x4E = quad_perm(2,3,0,1) -> lane^2
template<int CTRL>
__device__ __forceinline__ float dpp_xor(float x) {
  int r = __builtin_amdgcn_update_dpp(0, __builtin_bit_cast(int, x),
                                      CTRL, 0xF, 0xF, true);
  return __builtin_bit_cast(float, r);
}
// barrier that makes LDS writes visible WITHOUT draining vmcnt (global
// stores / prefetch loads keep flying across steps)
__device__ __forceinline__ void barrier_lds() {
  asm volatile("s_waitcnt lgkmcnt(0)" ::: "memory");
  __builtin_amdgcn_s_barrier();
  asm volatile("" ::: "memory");
}

// ---------------------------------------------------------------------------
// Weight convert + hi/lo split. Whh pre-scaled by CSC (tanh exp2 fold).
// f16 layout: WinH[32768] WinL[32768] WihH[65536] WihL[65536] Whh[65536] Wout[32768]
// (unchanged, proven)
// ---------------------------------------------------------------------------
__global__ void cvt_weights(const float* __restrict__ Win, const float* __restrict__ Wih,
                            const float* __restrict__ Whh, const float* __restrict__ Wout,
                            f16* __restrict__ dst) {
  int i = blockIdx.x * blockDim.x + threadIdx.x;
  if (i < 32768) {
    float v = Win[i]; f16 h = (f16)v;
    dst[i] = h; dst[32768 + i] = (f16)(v - (float)h);
  } else if (i < 98304) {
    int j = i - 32768; float v = Wih[j]; f16 h = (f16)v;
    dst[65536 + j] = h; dst[131072 + j] = (f16)(v - (float)h);
  } else if (i < 163840) {
    int j = i - 98304; dst[196608 + j] = (f16)(CSC * Whh[j]);
  } else if (i < 196608) {
    int j = i - 163840; dst[262144 + j] = (f16)Wout[j];
  }
}

// ---------------------------------------------------------------------------
// GEMM: C[m,n] = act( sum_k A[m,k]*W[n,k] + bias[n] )   (R20 version, proven:
// A-side lo path removed; B-side hi/lo kept — dominant W-quant term corrected)
// ---------------------------------------------------------------------------
constexpr int BM = 64, BN = 64, BK = 64;

template<int MODE>
__global__ __launch_bounds__(256)
void gemm_kernel(const void* __restrict__ Ap,
                 const f16* __restrict__ Bh_, const f16* __restrict__ Bl_,
                 const float* __restrict__ bias, const float* __restrict__ bias2,
                 void* __restrict__ Cp, int K, int N) {
  __shared__ __align__(16) f16 Ah[BM][BK + 8];
  __shared__ __align__(16) f16 Bh[BN][BK + 8];
  __shared__ __align__(16) f16 Bl[BN][BK + 8];

  const int tid  = threadIdx.x;
  const int lane = tid & 63;
  const int wid  = tid >> 6;
  const int wm = wid >> 1, wn = wid & 1;
  const long row0 = (long)blockIdx.x * BM;
  const int  col0 = blockIdx.y * BN;
  const int r  = tid >> 2;
  const int cc = (tid & 3) * 16;

  f32x4 acc[2][2] = {};

  for (int k0 = 0; k0 < K; k0 += BK) {
    if constexpr (MODE == 1) {
      const float* src = (const float*)Ap + (row0 + r) * (long)K + k0 + cc;
      #pragma unroll
      for (int q = 0; q < 4; ++q) {
        float4 v = ((const float4*)src)[q];
        Ah[r][cc + 4*q + 0] = (f16)v.x;
        Ah[r][cc + 4*q + 1] = (f16)v.y;
        Ah[r][cc + 4*q + 2] = (f16)v.z;
        Ah[r][cc + 4*q + 3] = (f16)v.w;
      }
    } else {
      const f16* sh = (const f16*)Ap + (row0 + r) * (long)K + k0 + cc;
      *(uint4*)&Ah[r][cc]     = *(const uint4*)sh;
      *(uint4*)&Ah[r][cc + 8] = *(const uint4*)(sh + 8);
    }
    {
      const f16* sh = Bh_ + (col0 + r) * (long)K + k0 + cc;
      *(uint4*)&Bh[r][cc]     = *(const uint4*)sh;
      *(uint4*)&Bh[r][cc + 8] = *(const uint4*)(sh + 8);
      if constexpr (MODE != 3) {
        const f16* sl = Bl_ + (col0 + r) * (long)K + k0 + cc;
        *(uint4*)&Bl[r][cc]     = *(const uint4*)sl;
        *(uint4*)&Bl[r][cc + 8] = *(const uint4*)(sl + 8);
      }
    }
    __syncthreads();

    #pragma unroll
    for (int ks = 0; ks < BK / 32; ++ks) {
      const int ko = ks * 32 + (lane >> 4) * 8;
      const int ra = wm * 32 + (lane & 15);
      const int rb = wn * 32 + (lane & 15);
      f16x8 a0 = *(const f16x8*)&Ah[ra][ko];
      f16x8 a1 = *(const f16x8*)&Ah[ra + 16][ko];
      f16x8 b0 = *(const f16x8*)&Bh[rb][ko];
      f16x8 b1 = *(const f16x8*)&Bh[rb + 16][ko];
      acc[0][0] = __builtin_amdgcn_mfma_f32_16x16x32_f16(a0, b0, acc[0][0], 0, 0, 0);
      acc[0][1] = __builtin_amdgcn_mfma_f32_16x16x32_f16(a0, b1, acc[0][1], 0, 0, 0);
      acc[1][0] = __builtin_amdgcn_mfma_f32_16x16x32_f16(a1, b0, acc[1][0], 0, 0, 0);
      acc[1][1] = __builtin_amdgcn_mfma_f32_16x16x32_f16(a1, b1, acc[1][1], 0, 0, 0);
      if constexpr (MODE != 3) {
        f16x8 lb0 = *(const f16x8*)&Bl[rb][ko];
        f16x8 lb1 = *(const f16x8*)&Bl[rb + 16][ko];
        acc[0][0] = __builtin_amdgcn_mfma_f32_16x16x32_f16(a0, lb0, acc[0][0], 0, 0, 0);
        acc[0][1] = __builtin_amdgcn_mfma_f32_16x16x32_f16(a0, lb1, acc[0][1], 0, 0, 0);
        acc[1][0] = __builtin_amdgcn_mfma_f32_16x16x32_f16(a1, lb0, acc[1][0], 0, 0, 0);
        acc[1][1] = __builtin_amdgcn_mfma_f32_16x16x32_f16(a1, lb1, acc[1][1], 0, 0, 0);
      }
    }
    __syncthreads();
  }

  #pragma unroll
  for (int mi = 0; mi < 2; ++mi)
    #pragma unroll
    for (int ni = 0; ni < 2; ++ni)
      #pragma unroll
      for (int q = 0; q < 4; ++q) {
        long row = row0 + wm * 32 + mi * 16 + (lane >> 4) * 4 + q;
        int  col = col0 + wn * 32 + ni * 16 + (lane & 15);
        if constexpr (MODE == 1) {
          float v = fmaxf(acc[mi][ni][q] + bias[col], 0.0f);
          ((f16*)Cp)[row * (long)N + col] = (f16)v;
        } else if constexpr (MODE == 2) {
          float v = (acc[mi][ni][q] + bias[col] + bias2[col]) * CSC;
          ((float*)Cp)[row * (long)N + col] = v;
        } else {
          ((float*)Cp)[row * (long)N + col] = acc[mi][ni][q] + bias[col];
        }
      }
}

// ---------------------------------------------------------------------------
// Recurrence: VERBATIM R12 (the session-best 887us kernel, VGPR 48).
// Final verdict after R13-R19, R21: this structure is a hard local optimum.
// It is ISSUE/LATENCY-bound (65% per-CU VALUBusy: 64 fdot2 + remat loads +
// serial chain ARE the step) — not L2-BW-bound (R21 falsified: port-split
// added 210 cyc), not LDS-bound (R15: halving reads no gain), and register
// residency of Whh is compiler-unreachable (R16-R19: VGPR pinned 32-80
// regardless of pins/bounds/aliasing; MFMA variants add copy storms).
// Structural ceiling: 2048 serial steps x ~435ns of issue+LDS-roundtrip+
// barrier on one CU per batch chain. Do not touch.
// ---------------------------------------------------------------------------
#define STEP(K, SRC, DST, P) do {                                            \
  unsigned int hs[32];                                                       \
  _Pragma("unroll")                                                          \
  for (int q = 0; q < 8; ++q) {                                              \
    uint4 v = *(const uint4*)((SRC) + roff[q]);                              \
    hs[4*q+0] = v.x; hs[4*q+1] = v.y; hs[4*q+2] = v.z; hs[4*q+3] = v.w;      \
  }                                                                          \
  float a0a = 0.f, a1a = 0.f, a0b = 0.f, a1b = 0.f;                          \
  _Pragma("unroll")                                                          \
  for (int kk = 0; kk < 16; ++kk) {                                          \
    a0a = fdot2f(wr0[kk], hs[kk], a0a);                                      \
    a1a = fdot2f(wr1[kk], hs[kk], a1a);                                      \
  }                                                                          \
  _Pragma("unroll")                                                          \
  for (int kk = 16; kk < 32; ++kk) {                                         \
    a0b = fdot2f(wr0[kk], hs[kk], a0b);                                      \
    a1b = fdot2f(wr1[kk], hs[kk], a1b);                                      \
  }                                                                          \
  float a0 = a0a + a0b, a1 = a1a + a1b;                                      \
  float keep = s0 ? a1 : a0;                                                 \
  float send = s0 ? a0 : a1;                                                 \
  float t1 = keep + dpp_xor<0xB1>(send);    /* xor1, quad_perm(1,0,3,2) */   \
  float z  = t1 + dpp_xor<0x4E>(t1) + (P);  /* xor2 all-reduce */            \
  float ee = exp2f_hw(z);                                                    \
  float hv = fmaxf(fmaf(-2.0f, rcp_hw(ee + 1.0f), 1.0f), 0.0f);              \
  f16 hf = (f16)hv;                                                          \
  if (!s1) *(f16*)((DST) + wo) = hf;        /* LDS next-h (one copy) */      \
  else     hp[(K) * 256] = hf;              /* h16 global (other copy) */    \
} while (0)

__global__ __launch_bounds__(512, 1)
void rec_kernel(const float* __restrict__ pre, const f16* __restrict__ W2,
                f16* __restrict__ h16) {
  const int b    = blockIdx.x;
  const int tid  = threadIdx.x;
  const int lane = tid & 63;
  const int w    = tid >> 6;                 // 0..7
  const int jj   = lane & 3;                 // k-slice [64jj,64jj+64)
  const int grp  = (lane >> 2) | (w << 4);   // 0..127
  const int s0   = lane & 1;
  const int s1   = (lane >> 1) & 1;
  const int G    = grp * 2;
  const int g    = G + s0;                   // owned output (dup with lane^2)

  __shared__ __align__(16) char hb[2][512];

  // W rows G, G+1, k in [64jj,64jj+64), chunk-rotated to match LDS reads
  unsigned int wr0[32], wr1[32];
  #pragma unroll
  for (int q = 0; q < 8; ++q) {
    int c = (q + 2 * jj) & 7;
    uint4 v0 = *(const uint4*)(W2 + (size_t)G * 256 + 64 * jj + 8 * c);
    uint4 v1 = *(const uint4*)(W2 + (size_t)(G + 1) * 256 + 64 * jj + 8 * c);
    wr0[4*q+0] = v0.x; wr0[4*q+1] = v0.y; wr0[4*q+2] = v0.z; wr0[4*q+3] = v0.w;
    wr1[4*q+0] = v1.x; wr1[4*q+1] = v1.y; wr1[4*q+2] = v1.z; wr1[4*q+3] = v1.w;
  }
  if (tid < 128) ((unsigned int*)&hb[0][0])[tid] = 0u;
  __syncthreads();

  int roff[8];
  #pragma unroll
  for (int q = 0; q < 8; ++q) roff[q] = 128 * jj + 16 * ((q + 2 * jj) & 7);
  const int wo = 2 * g;

  const float* pp  = pre + (size_t)b * TLEN * 256 + g;
  f16*         hp  = h16 + (size_t)b * TLEN * 256 + g;
  const float* ppf = pp + 1024;              // t+4 prefetch pointer

  float p0 = pp[0];
  float p1 = pp[256];
  float p2 = pp[512];
  float p3 = pp[768];

  const char* hb0 = &hb[0][0];
  char*       hb1 = &hb[1][0];

  #pragma unroll 1
  for (int t = 0; t < TLEN; t += 4) {
    // issue next-quad prefetch early; lands during these 4 steps
    float n0 = ppf[0];
    float n1 = ppf[256];
    float n2 = ppf[512];
    float n3 = ppf[768];
    STEP(0, hb0, hb1, p0);
    barrier_lds();
    STEP(1, hb1, (char*)hb0, p1);
    barrier_lds();
    STEP(2, hb0, hb1, p2);
    barrier_lds();
    STEP(3, hb1, (char*)hb0, p3);
    barrier_lds();
    p0 = n0; p1 = n1; p2 = n2; p3 = n3;
    ppf += 1024;
    hp  += 1024;
  }
}

// ---------------------------------------------------------------------------
// h16 -> f32 hidden (parallel, HBM-bound; removes the f32 store from rec's
// serial loop). Proven in R2.
// ---------------------------------------------------------------------------
__global__ __launch_bounds__(256)
void cvt_h(const f16* __restrict__ src, float* __restrict__ dst, long n) {
  long i0 = ((long)blockIdx.x * 256 + threadIdx.x) * 8;
  long stride = (long)gridDim.x * 256 * 8;
  for (long i = i0; i < n; i += stride) {
    f16x8 v = *(const f16x8*)(src + i);
    float4 a = {(float)v[0], (float)v[1], (float)v[2], (float)v[3]};
    float4 bq = {(float)v[4], (float)v[5], (float)v[6], (float)v[7]};
    *(float4*)(dst + i) = a;
    *(float4*)(dst + i + 4) = bq;
  }
}

// ---------------------------------------------------------------------------
extern "C" void kernel_launch(void* const* d_in, const int* in_sizes, int n_in,
                              void* d_out, int out_size, void* d_ws, size_t ws_size,
                              hipStream_t stream) {
  const float* input = (const float*)d_in[0];
  const float* W_in  = (const float*)d_in[1];
  const float* b_in  = (const float*)d_in[2];
  const float* W_ih  = (const float*)d_in[3];
  const float* b_ih  = (const float*)d_in[4];
  const float* W_hh  = (const float*)d_in[5];
  const float* b_hh  = (const float*)d_in[6];
  const float* W_out = (const float*)d_in[7];
  const float* b_out = (const float*)d_in[8];

  float* hidden = (float*)d_out;                   // [64,2048,256] f32
  float* outp   = (float*)d_out + MROWS * NHID;    // [64,2048,128] f32

  char* ws = (char*)d_ws;
  const size_t xh_off  = 0;
  const size_t xl_off  = (size_t)MROWS * NHID * 2;       // 64 MiB (unused now)
  const size_t pre_off = xl_off * 2;                     // 128 MiB in
  const size_t w_off   = pre_off + (size_t)MROWS * NHID * 4;
  const size_t need    = w_off + 294912ull * 2;
  if (ws_size < need) return;

  f16*   x_hi  = (f16*)(ws + xh_off);
  float* pre   = (float*)(ws + pre_off);                 // plain [b][t][g], scaled
  f16*   wbase = (f16*)(ws + w_off);
  f16 *WinH = wbase,           *WinL = wbase + 32768;
  f16 *WihH = wbase + 65536,   *WihL = wbase + 131072;
  f16 *Whh16 = wbase + 196608, *Wout16 = wbase + 262144;
  f16* h16 = x_hi;   // alias: x consumed by G2 before rec writes h16

  cvt_weights<<<768, 256, 0, stream>>>(W_in, W_ih, W_hh, W_out, wbase);

  dim3 g12((unsigned)(MROWS / BM), NHID / BN);
  gemm_kernel<1><<<g12, 256, 0, stream>>>(input, WinH, WinL, b_in, nullptr,
                                          x_hi, NIN, NHID);
  gemm_kernel<2><<<g12, 256, 0, stream>>>(x_hi, WihH, WihL, b_ih, b_hh,
                                          pre, NHID, NHID);

  rec_kernel<<<BATCH, 512, 0, stream>>>(pre, Whh16, h16);

  cvt_h<<<2048, 256, 0, stream>>>(h16, hidden, MROWS * NHID);

  dim3 g3((unsigned)(MROWS / BM), NOUT / BN);
  gemm_kernel<3><<<g3, 256, 0, stream>>>(h16, Wout16, nullptr, b_out, nullptr,
                                         outp, NHID, NOUT);
}